// Round 15
// baseline (436.719 us; speedup 1.0000x reference)
//
#include <hip/hip_runtime.h>
#include <hip/hip_bf16.h>
#include <math.h>

#define NN 50000
#define EE 800000
#define HH 128
#define CHH 64
#define LL 3
#define ZT (NN * HH)
#define NBK 196          // ceil(50000/256) node buckets
#define EPB 3125         // EE / 256 edges per sort block

using bf16 = __hip_bfloat16;
typedef unsigned short u16;
typedef unsigned int u32;
typedef __attribute__((ext_vector_type(8))) short s16x8;
typedef __attribute__((ext_vector_type(4))) float f32x4;

__device__ __forceinline__ float ldbf(const u16* p, size_t i) {
    return __uint_as_float(((u32)p[i]) << 16);
}
__device__ __forceinline__ u16 f2b(float v) {
    bf16 b = __float2bfloat16(v);
    return *reinterpret_cast<u16*>(&b);
}
__device__ __forceinline__ void stbf(u16* p, size_t i, float v) { p[i] = f2b(v); }
__device__ __forceinline__ float blo(u32 w) { return __uint_as_float(w << 16); }
__device__ __forceinline__ float bhi(u32 w) { return __uint_as_float(w & 0xFFFF0000u); }

// ---- zero-fill fallback (diagnostic signature) ----
__global__ __launch_bounds__(256) void zero_out_k(float* __restrict__ out, int n) {
    int i = blockIdx.x * 256 + threadIdx.x;
    if (i < n) out[i] = 0.f;
}

// ---- init: h=bf16(x), flags ----
__global__ __launch_bounds__(256) void init_k(const float* __restrict__ x, u16* __restrict__ h,
        int* __restrict__ softex, int* __restrict__ hardex, int* __restrict__ exitl,
        int* __restrict__ act) {
    int i = blockIdx.x * 256 + threadIdx.x;
    if (i < ZT) stbf(h, (size_t)i, x[i]);
    if (i < NN) { softex[i] = 0; hardex[i] = 0; exitl[i] = LL; }
    if (i < LL) act[i] = 0;
}

// ---- sort phase 1: both bucket histograms in one edge pass ----
__global__ __launch_bounds__(256) void hist_both_k(const int* __restrict__ ei,
        int* __restrict__ hist1, int* __restrict__ hist2) {
    __shared__ int h1[NBK], h2[NBK];
    int t = threadIdx.x, b = blockIdx.x;
    if (t < NBK) { h1[t] = 0; h2[t] = 0; }
    __syncthreads();
    int base = b * EPB;
    for (int i = t; i < EPB; i += 256) {
        int e = base + i;
        int s = ei[e], d = ei[EE + e];
        if ((u32)s >= NN || (u32)d >= NN) continue;
        atomicAdd(&h1[d >> 8], 1);                 // in-CSR: key=dst, keep self
        if (s != d) atomicAdd(&h2[s >> 8], 1);     // out-CSR: key=src, skip self
    }
    __syncthreads();
    if (t < NBK) { hist1[b * NBK + t] = h1[t]; hist2[b * NBK + t] = h2[t]; }
}

// ---- sort phase 2: offsets per (bucket, block) + bucket starts ----
__global__ __launch_bounds__(256) void boffs_k(const int* __restrict__ hist,
        int* __restrict__ boffs, int* __restrict__ bstart) {
    int t = threadIdx.x;
    __shared__ int scn[256];
    int run = 0;
    if (t < NBK) {
        for (int b = 0; b < 256; ++b) {
            boffs[t * 256 + b] = run;
            run += hist[b * NBK + t];
        }
    }
    int v = (t < NBK) ? run : 0;
    scn[t] = v;
    __syncthreads();
    for (int off = 1; off < 256; off <<= 1) {
        int x = (t >= off) ? scn[t - off] : 0;
        __syncthreads();
        scn[t] += x;
        __syncthreads();
    }
    int excl = scn[t] - v;
    if (t < NBK) {
        bstart[t] = excl;
        if (t == NBK - 1) bstart[NBK] = excl + v;
        for (int b = 0; b < 256; ++b) boffs[t * 256 + b] += excl;
    }
}

// ---- sort phase 3: scatter both ebufs in one edge pass (LDS cursors) ----
__global__ __launch_bounds__(256) void scat_both_k(const int* __restrict__ ei,
        const int* __restrict__ boffs1, u32* __restrict__ ebuf1,
        const int* __restrict__ boffs2, u32* __restrict__ ebuf2) {
    __shared__ int c1[NBK], c2[NBK];
    int t = threadIdx.x, b = blockIdx.x;
    if (t < NBK) { c1[t] = boffs1[t * 256 + b]; c2[t] = boffs2[t * 256 + b]; }
    __syncthreads();
    int base = b * EPB;
    for (int i = t; i < EPB; i += 256) {
        int e = base + i;
        int s = ei[e], d = ei[EE + e];
        if ((u32)s >= NN || (u32)d >= NN) continue;
        int pos = atomicAdd(&c1[d >> 8], 1);
        ebuf1[pos] = (u32)s | ((u32)(d & 255) << 16);
        if (s != d) {
            int pos2 = atomicAdd(&c2[s >> 8], 1);
            ebuf2[pos2] = (u32)d | ((u32)(s & 255) << 16);
        }
    }
}

// ---- sort phase 4 body: per-bucket fine CSR fill (+ optional dinv) ----
__device__ __forceinline__ void fine_body(int bk, const u32* __restrict__ ebuf,
        const int* __restrict__ bstart, int* __restrict__ rowptr, u16* __restrict__ csrx,
        float* __restrict__ dinv, int addself) {
    __shared__ int cnt[256];
    __shared__ int scn[256];
    int t = threadIdx.x;
    int eb = bstart[bk], ee = bstart[bk + 1];
    cnt[t] = 0;
    __syncthreads();
    for (int i = eb + t; i < ee; i += 256)
        atomicAdd(&cnt[(ebuf[i] >> 16) & 255], 1);
    __syncthreads();
    int v = cnt[t];
    scn[t] = v;
    __syncthreads();
    for (int off = 1; off < 256; off <<= 1) {
        int x = (t >= off) ? scn[t - off] : 0;
        __syncthreads();
        scn[t] += x;
        __syncthreads();
    }
    int excl = scn[t] - v;
    int n = (bk << 8) + t;
    if (n < NN) {
        rowptr[n] = eb + excl;
        if (dinv) dinv[n] = 1.0f / sqrtf((float)(v + addself));
    }
    if (bk == NBK - 1 && t == 0) rowptr[NN] = ee;
    __syncthreads();
    cnt[t] = excl;   // reuse as cursor
    __syncthreads();
    for (int i = eb + t; i < ee; i += 256) {
        u32 w = ebuf[i];
        int lo = (w >> 16) & 255;
        int pos = atomicAdd(&cnt[lo], 1);
        csrx[eb + pos] = (u16)(w & 0xFFFF);
    }
}

__global__ __launch_bounds__(256) void fine2_k(const u32* __restrict__ ebuf1,
        const int* __restrict__ bstart1, int* __restrict__ irow, u16* __restrict__ csrc,
        float* __restrict__ dinv, const u32* __restrict__ ebuf2,
        const int* __restrict__ bstart2, int* __restrict__ orow, u16* __restrict__ ocol) {
    if (blockIdx.x < NBK) fine_body(blockIdx.x, ebuf1, bstart1, irow, csrc, dinv, 1);
    else                  fine_body(blockIdx.x - NBK, ebuf2, bstart2, orow, ocol, nullptr, 0);
}

// ---- pack weights: wt[mat][o][k] = bf16(W[k][o]); mats 0..2 conv, 3 = [sw1|hw1] ----
__global__ __launch_bounds__(256) void pack_w_k(const float* __restrict__ w0,
        const float* __restrict__ w1, const float* __restrict__ w2,
        const float* __restrict__ sw1, const float* __restrict__ hw1, u16* __restrict__ wt) {
    int i = blockIdx.x * 256 + threadIdx.x;
    if (i >= 4 * HH * HH) return;
    int mat = i >> 14, rr = i & 16383, o = rr >> 7, k = rr & 127;
    float v;
    if (mat == 0) v = w0[k * HH + o];
    else if (mat == 1) v = w1[k * HH + o];
    else if (mat == 2) v = w2[k * HH + o];
    else v = (o < CHH) ? sw1[k * CHH + o] : hw1[k * CHH + (o - CHH)];
    stbf(wt, (size_t)i, v);
}

// ---- quarter-split gather: block = 16 nodes x 16 lanes, one 32-ch quarter ----
// quarter chosen by blockIdx&7 (round-robin XCD): each quarter confined to 2 XCDs,
// whose L2 then holds the 3.2MB h-quarter. Mapping is perf-only, not correctness.
__global__ __launch_bounds__(256) void gather4_k(const int* __restrict__ irow,
        const u16* __restrict__ csrc, const float* __restrict__ dinv,
        const u16* __restrict__ hg, u16* __restrict__ hinb) {
    int bid = blockIdx.x;
    int c8 = bid & 7;
    int q = c8 >> 1;                         // channel quarter 0..3
    int idx = (bid >> 3) * 2 + (c8 & 1);     // node-group 0..3124
    if (idx >= NN / 16) return;
    int t = threadIdx.x;
    int node = idx * 16 + (t >> 4);
    int l = t & 15;
    int co = q * 32 + l * 2;                 // channel offset (u16 units)
    int beg = irow[node], end = irow[node + 1];
    float dvd = dinv[node];
    float a0 = 0.f, a1 = 0.f;
    int e = beg;
    for (; e + 3 < end; e += 4) {
        int s0 = csrc[e], s1 = csrc[e + 1], s2 = csrc[e + 2], s3 = csrc[e + 3];
        float n0 = dinv[s0], n1 = dinv[s1], n2 = dinv[s2], n3 = dinv[s3];
        u32 w0 = *(const u32*)(hg + (size_t)s0 * HH + co);
        u32 w1 = *(const u32*)(hg + (size_t)s1 * HH + co);
        u32 w2 = *(const u32*)(hg + (size_t)s2 * HH + co);
        u32 w3 = *(const u32*)(hg + (size_t)s3 * HH + co);
        a0 = fmaf(n0, blo(w0), a0); a1 = fmaf(n0, bhi(w0), a1);
        a0 = fmaf(n1, blo(w1), a0); a1 = fmaf(n1, bhi(w1), a1);
        a0 = fmaf(n2, blo(w2), a0); a1 = fmaf(n2, bhi(w2), a1);
        a0 = fmaf(n3, blo(w3), a0); a1 = fmaf(n3, bhi(w3), a1);
    }
    for (; e < end; ++e) {
        int s0 = csrc[e];
        float n0 = dinv[s0];
        u32 w0 = *(const u32*)(hg + (size_t)s0 * HH + co);
        a0 = fmaf(n0, blo(w0), a0); a1 = fmaf(n0, bhi(w0), a1);
    }
    a0 *= dvd; a1 *= dvd;
    u32 hw = *(const u32*)(hg + (size_t)node * HH + co);
    float self = dvd * dvd;                  // self-loop norm (ref gcn_norm)
    a0 = fmaf(blo(hw), self, a0);
    a1 = fmaf(bhi(hw), self, a1);
    ((u32*)hinb)[(size_t)node * 64 + q * 16 + l] = (u32)f2b(a0) | ((u32)f2b(a1) << 16);
}

// ---- gemm+heads: h = act(hinb@Wc+b); P = h@[sw1|hw1]; soft decision in-register ----
// block: 16 rows, 4 waves; P-hard half stored f32 into out z-region (rows not yet exited)
__global__ __launch_bounds__(256) void gemmheads_k(int li, int geluf,
        const u16* __restrict__ hinb, u16* __restrict__ hout_g,
        const u16* __restrict__ Wc, const u16* __restrict__ Wh, const float* __restrict__ bias,
        const float* __restrict__ sb1, const float* __restrict__ sw2, const float* __restrict__ sb2,
        const float* __restrict__ gs, int* __restrict__ softex, const int* __restrict__ hardex,
        float* __restrict__ outP) {
    __shared__ u16 hl[16 * HH];                 // swizzled h tile for GEMM2
    __shared__ float l0s[2][16], l1s[2][16];
    __shared__ int hx[16];
    int tid = threadIdx.x;
    int wave = tid >> 6, lane = tid & 63;
    int row0 = blockIdx.x * 16;
    if (tid < 16) hx[tid] = hardex[row0 + tid];
    int r = lane & 15, g = lane >> 4;
    // ---- GEMM1 (conv), A from global hinb ----
    const u16* arow = hinb + (size_t)(row0 + r) * HH;
    s16x8 af[4];
    #pragma unroll
    for (int kk = 0; kk < 4; ++kk) af[kk] = *(const s16x8*)(arow + kk * 32 + g * 8);
    f32x4 acc[2];
    #pragma unroll
    for (int cc = 0; cc < 2; ++cc) {
        int c0 = wave * 32 + cc * 16;
        const u16* brow = Wc + (size_t)(c0 + r) * HH;
        f32x4 a = {0.f, 0.f, 0.f, 0.f};
        #pragma unroll
        for (int kk = 0; kk < 4; ++kk) {
            s16x8 b = *(const s16x8*)(brow + kk * 32 + g * 8);
            a = __builtin_amdgcn_mfma_f32_16x16x32_bf16(af[kk], b, a, 0, 0, 0);
        }
        acc[cc] = a;
    }
    #pragma unroll
    for (int cc = 0; cc < 2; ++cc) {
        int col = wave * 32 + cc * 16 + r;
        float bv = bias[col];
        #pragma unroll
        for (int j = 0; j < 4; ++j) {
            int row = g * 4 + j;
            float v = acc[cc][j] + bv;
            if (geluf) v = 0.5f * v * (1.0f + erff(v * 0.70710678118654752f));
            stbf(hout_g, (size_t)(row0 + row) * HH + col, v);
            int chunk = (col >> 3) ^ (row & 7);            // XOR swizzle (G4)
            hl[row * HH + chunk * 8 + (col & 7)] = f2b(v);
        }
    }
    __syncthreads();
    // ---- GEMM2 (heads), A from swizzled LDS ----
    #pragma unroll
    for (int kk = 0; kk < 4; ++kk) {
        int k0 = kk * 32 + g * 8;
        int chunk = (k0 >> 3) ^ (r & 7);
        af[kk] = *(const s16x8*)(hl + r * HH + chunk * 8);
    }
    #pragma unroll
    for (int cc = 0; cc < 2; ++cc) {
        int c0 = wave * 32 + cc * 16;
        const u16* brow = Wh + (size_t)(c0 + r) * HH;
        f32x4 a = {0.f, 0.f, 0.f, 0.f};
        #pragma unroll
        for (int kk = 0; kk < 4; ++kk) {
            s16x8 b = *(const s16x8*)(brow + kk * 32 + g * 8);
            a = __builtin_amdgcn_mfma_f32_16x16x32_bf16(af[kk], b, a, 0, 0, 0);
        }
        acc[cc] = a;
    }
    if (wave < 2) {
        float pl0[4] = {0.f, 0.f, 0.f, 0.f}, pl1[4] = {0.f, 0.f, 0.f, 0.f};
        #pragma unroll
        for (int cc = 0; cc < 2; ++cc) {
            int col = wave * 32 + cc * 16 + r;
            float b1 = sb1[col], w20 = sw2[col * 2], w21 = sw2[col * 2 + 1];
            #pragma unroll
            for (int j = 0; j < 4; ++j) {
                float hv = fmaxf(acc[cc][j] + b1, 0.f);
                pl0[j] = fmaf(hv, w20, pl0[j]);
                pl1[j] = fmaf(hv, w21, pl1[j]);
            }
        }
        #pragma unroll
        for (int off = 1; off < 16; off <<= 1) {
            #pragma unroll
            for (int j = 0; j < 4; ++j) {
                pl0[j] += __shfl_xor(pl0[j], off);
                pl1[j] += __shfl_xor(pl1[j], off);
            }
        }
        if (r == 0) {
            #pragma unroll
            for (int j = 0; j < 4; ++j) {
                l0s[wave][g * 4 + j] = pl0[j];
                l1s[wave][g * 4 + j] = pl1[j];
            }
        }
    } else {
        #pragma unroll
        for (int cc = 0; cc < 2; ++cc) {
            int col = wave * 32 + cc * 16 + r;
            #pragma unroll
            for (int j = 0; j < 4; ++j) {
                int row = g * 4 + j;
                if (!hx[row]) outP[(size_t)(row0 + row) * HH + col] = acc[cc][j];
            }
        }
    }
    __syncthreads();
    if (tid < 16) {
        int n = row0 + tid;
        float l0 = l0s[0][tid] + l0s[1][tid] + sb2[0];
        float l1 = l1s[0][tid] + l1s[1][tid] + sb2[1];
        const float* gg = gs + ((size_t)li * NN + n) * 2;
        if (l1 + gg[1] > l0 + gg[0]) softex[n] = 1;
    }
}

// ---- hard finish: readiness gather over out-CSR; P read f32 from out z-region ----
__global__ __launch_bounds__(256) void hard_fin_k(int li,
        const u16* __restrict__ h, const float* __restrict__ hw1, const float* __restrict__ hb1,
        const float* __restrict__ hw2, const float* __restrict__ hb2,
        const float* __restrict__ gh, const int* __restrict__ softex,
        int* __restrict__ hardex, int* __restrict__ exitl,
        const int* __restrict__ orow, const u16* __restrict__ ocol,
        float* __restrict__ out) {
    int t = threadIdx.x;
    int n = blockIdx.x * 4 + (t >> 6);
    int j = t & 63;
    if (!softex[n] || hardex[n]) return;   // wave-uniform; non-soft-exited never hard-exit (1e6 margin)
    int ob = orow[n], oe = orow[n + 1];
    int cnt = 0;
    for (int e = ob + j; e < oe; e += 64) cnt += softex[ocol[e]];
    #pragma unroll
    for (int off = 32; off > 0; off >>= 1) cnt += __shfl_xor(cnt, off);
    int dns = oe - ob; if (dns < 1) dns = 1;
    float r = (float)cnt / (float)dns;
    float pv = out[(size_t)n * HH + CHH + j];
    float hid = fmaxf(pv + r * hw1[HH * CHH + j] + hb1[j], 0.f);
    float l0 = hid * hw2[j * 2], l1 = hid * hw2[j * 2 + 1];
    #pragma unroll
    for (int off = 32; off > 0; off >>= 1) {
        l0 += __shfl_xor(l0, off);   // butterfly: identical sums on all lanes
        l1 += __shfl_xor(l1, off);
    }
    const float* g = gh + ((size_t)li * NN + n) * 2;
    if (l1 + hb2[1] + g[1] > l0 + hb2[0] + g[0]) {
        if (j == 0) { hardex[n] = 1; exitl[n] = li; }
        u32 hw = *(const u32*)(h + (size_t)n * HH + j * 2);
        out[(size_t)n * HH + j * 2]     = blo(hw);
        out[(size_t)n * HH + j * 2 + 1] = bhi(hw);
    }
}

// ---- tail: non-exited z rows + exit_layers; per-block exit histogram -> act ----
__global__ __launch_bounds__(256) void tail_k(const u16* __restrict__ h, const int* __restrict__ exitl,
        float* __restrict__ out, int* __restrict__ act) {
    __shared__ int c[LL];
    int t = threadIdx.x;
    int i = blockIdx.x * 256 + t;
    if (t < LL) c[t] = 0;
    __syncthreads();
    if (i < ZT) {
        int n = i >> 7;
        if (exitl[n] == LL) out[i] = ldbf(h, (size_t)i);
    } else if (i < ZT + NN) {
        int e = exitl[i - ZT];
        out[i] = (float)e;
        if (e < LL) atomicAdd(&c[e], 1);
    }
    __syncthreads();
    if (t < LL && c[t]) atomicAdd(&act[t], c[t]);
}

// ---- finalize active counts ----
__global__ __launch_bounds__(64) void finalize_k(const int* __restrict__ act, float* __restrict__ out) {
    if (threadIdx.x == 0) {
        out[ZT + NN]     = (float)NN;
        out[ZT + NN + 1] = (float)(NN - act[0]);
        out[ZT + NN + 2] = (float)(NN - act[0] - act[1]);
    }
}

extern "C" void kernel_launch(void* const* d_in, const int* in_sizes, int n_in,
                              void* d_out, int out_size, void* d_ws, size_t ws_size,
                              hipStream_t stream) {
    float* out = (float*)d_out;                 // output is FLOAT32
    const int OUT_N = ZT + NN + LL;

    static const int CANON[19] = {6400000,1600000,300000,300000,16384,128,16384,128,16384,128,
                                  8192,64,128,2,8256,64,128,2,128};
    static const int SORTED_ROLE[19] = {5,7,9,4,6,8,1,3,2,15,17,14,16,11,13,10,12,18,0};
    int perm[19];
    bool ok = (n_in == 19);
    if (ok) {
        bool mc = true, mr = true, ms = true;
        for (int i = 0; i < 19; ++i) {
            if (in_sizes[i] != CANON[i]) mc = false;
            if (in_sizes[i] != CANON[18 - i]) mr = false;
            if (in_sizes[i] != CANON[SORTED_ROLE[i]]) ms = false;
        }
        if (mc)      for (int c = 0; c < 19; ++c) perm[c] = c;
        else if (mr) for (int c = 0; c < 19; ++c) perm[c] = 18 - c;
        else if (ms) { for (int p = 0; p < 19; ++p) perm[SORTED_ROLE[p]] = p; }
        else         for (int c = 0; c < 19; ++c) perm[c] = c;
    }
    if (!ok) {
        zero_out_k<<<(OUT_N + 255) / 256, 256, 0, stream>>>(out, OUT_N);
        return;
    }

    const float* x  = (const float*)d_in[perm[0]];
    const int*   ei = (const int*)d_in[perm[1]];
    const float* gs = (const float*)d_in[perm[2]];
    const float* gh = (const float*)d_in[perm[3]];
    const float* cw[3] = { (const float*)d_in[perm[4]], (const float*)d_in[perm[6]], (const float*)d_in[perm[8]] };
    const float* cb[3] = { (const float*)d_in[perm[5]], (const float*)d_in[perm[7]], (const float*)d_in[perm[9]] };
    const float* sw1 = (const float*)d_in[perm[10]];
    const float* sb1 = (const float*)d_in[perm[11]];
    const float* sw2 = (const float*)d_in[perm[12]];
    const float* sb2 = (const float*)d_in[perm[13]];
    const float* hw1 = (const float*)d_in[perm[14]];
    const float* hb1 = (const float*)d_in[perm[15]];
    const float* hw2 = (const float*)d_in[perm[16]];
    const float* hb2 = (const float*)d_in[perm[17]];
    // temp_w unused: temp>0 always; softmax monotone -> decisions unaffected

    const size_t H_B    = (size_t)ZT * 2;      // 12.8 MB
    const size_t FLAG_B = 200192;
    const size_t ACT_B  = 256;
    const size_t RP_B   = 200704;              // 50001 ints padded
    const size_t CE_B   = (size_t)EE * 2;      // u16 CSR payloads
    const size_t WT_B   = 4 * HH * HH * 2;
    const size_t need = 2 * H_B + 4 * FLAG_B + ACT_B + 2 * RP_B + 2 * CE_B + WT_B;  // ~30.1 MB
    if (ws_size < need) {
        zero_out_k<<<(OUT_N + 255) / 256, 256, 0, stream>>>(out, OUT_N);
        return;
    }

    char* p = (char*)d_ws;
    u16* h    = (u16*)p; p += H_B;             // persistent h (in-place across layers)
    u16* hinb = (u16*)p; p += H_B;             // gather output; sort scratch pre-layers
    int* softex = (int*)p; p += FLAG_B;
    int* hardex = (int*)p; p += FLAG_B;
    int* exitl  = (int*)p; p += FLAG_B;
    float* dinv = (float*)p; p += FLAG_B;
    int* act    = (int*)p; p += ACT_B;
    int* irow   = (int*)p; p += RP_B;
    int* orow   = (int*)p; p += RP_B;
    u16* csrc   = (u16*)p; p += CE_B;
    u16* ocol   = (u16*)p; p += CE_B;
    u16* wt     = (u16*)p; p += WT_B;

    // sort scratch aliased into hinb (dead until layer-0 gather writes it)
    char* q = (char*)hinb;
    u32* ebuf1  = (u32*)q;  q += (size_t)EE * 4;
    u32* ebuf2  = (u32*)q;  q += (size_t)EE * 4;
    int* hist1  = (int*)q;  q += 256 * NBK * 4;
    int* hist2  = (int*)q;  q += 256 * NBK * 4;
    int* boffs1 = (int*)q;  q += NBK * 256 * 4;
    int* boffs2 = (int*)q;  q += NBK * 256 * 4;
    int* bstart1 = (int*)q; q += 1024;
    int* bstart2 = (int*)q; q += 1024;

    init_k<<<(ZT + 255) / 256, 256, 0, stream>>>(x, h, softex, hardex, exitl, act);

    hist_both_k<<<256, 256, 0, stream>>>(ei, hist1, hist2);
    boffs_k<<<1, 256, 0, stream>>>(hist1, boffs1, bstart1);
    boffs_k<<<1, 256, 0, stream>>>(hist2, boffs2, bstart2);
    scat_both_k<<<256, 256, 0, stream>>>(ei, boffs1, ebuf1, boffs2, ebuf2);
    fine2_k<<<2 * NBK, 256, 0, stream>>>(ebuf1, bstart1, irow, csrc, dinv,
                                         ebuf2, bstart2, orow, ocol);
    pack_w_k<<<(4 * HH * HH + 255) / 256, 256, 0, stream>>>(cw[0], cw[1], cw[2], sw1, hw1, wt);

    const int G4_GRID = ((NN / 16 + 1) / 2) * 8 + 8;   // 1563*8 = 12504
    for (int li = 0; li < LL; ++li) {
        int geluf = (li < LL - 1) ? 1 : 0;
        gather4_k<<<G4_GRID, 256, 0, stream>>>(irow, csrc, dinv, h, hinb);
        gemmheads_k<<<NN / 16, 256, 0, stream>>>(li, geluf, hinb, h,
                                                 wt + (size_t)li * HH * HH, wt + (size_t)3 * HH * HH,
                                                 cb[li], sb1, sw2, sb2, gs, softex, hardex, out);
        hard_fin_k<<<NN / 4, 256, 0, stream>>>(li, h, hw1, hb1, hw2, hb2, gh, softex,
                                               hardex, exitl, orow, ocol, out);
    }
    tail_k<<<(OUT_N + 255) / 256, 256, 0, stream>>>(h, exitl, out, act);
    finalize_k<<<1, 64, 0, stream>>>(act, out);
}

// Round 16
// 344.247 us; speedup vs baseline: 1.2686x; 1.2686x over previous
//
#include <hip/hip_runtime.h>
#include <hip/hip_bf16.h>
#include <math.h>

#define NN 50000
#define EE 800000
#define HH 128
#define CHH 64
#define LL 3
#define ZT (NN * HH)
#define NBK 196          // ceil(50000/256) node buckets
#define EPB 3125         // EE / 256 edges per sort block

using bf16 = __hip_bfloat16;
typedef unsigned short u16;
typedef unsigned int u32;
typedef __attribute__((ext_vector_type(8))) short s16x8;
typedef __attribute__((ext_vector_type(4))) float f32x4;

__device__ __forceinline__ float ldbf(const u16* p, size_t i) {
    return __uint_as_float(((u32)p[i]) << 16);
}
__device__ __forceinline__ u16 f2b(float v) {
    bf16 b = __float2bfloat16(v);
    return *reinterpret_cast<u16*>(&b);
}
__device__ __forceinline__ void stbf(u16* p, size_t i, float v) { p[i] = f2b(v); }
__device__ __forceinline__ float blo(u32 w) { return __uint_as_float(w << 16); }
__device__ __forceinline__ float bhi(u32 w) { return __uint_as_float(w & 0xFFFF0000u); }

// ---- zero-fill fallback (diagnostic signature) ----
__global__ __launch_bounds__(256) void zero_out_k(float* __restrict__ out, int n) {
    int i = blockIdx.x * 256 + threadIdx.x;
    if (i < n) out[i] = 0.f;
}

// ---- init: h=bf16(x), flags, both softex buffers ----
__global__ __launch_bounds__(256) void init_k(const float* __restrict__ x, u16* __restrict__ h,
        int* __restrict__ sx0, int* __restrict__ sx1, int* __restrict__ hardex,
        int* __restrict__ exitl, int* __restrict__ act) {
    int i = blockIdx.x * 256 + threadIdx.x;
    if (i < ZT) stbf(h, (size_t)i, x[i]);
    if (i < NN) { sx0[i] = 0; sx1[i] = 0; hardex[i] = 0; exitl[i] = LL; }
    if (i < LL) act[i] = 0;
}

// ---- sort phase 1: both bucket histograms in one edge pass ----
__global__ __launch_bounds__(256) void hist_both_k(const int* __restrict__ ei,
        int* __restrict__ hist1, int* __restrict__ hist2) {
    __shared__ int h1[NBK], h2[NBK];
    int t = threadIdx.x, b = blockIdx.x;
    if (t < NBK) { h1[t] = 0; h2[t] = 0; }
    __syncthreads();
    int base = b * EPB;
    for (int i = t; i < EPB; i += 256) {
        int e = base + i;
        int s = ei[e], d = ei[EE + e];
        if ((u32)s >= NN || (u32)d >= NN) continue;
        atomicAdd(&h1[d >> 8], 1);                 // in-CSR: key=dst, keep self
        if (s != d) atomicAdd(&h2[s >> 8], 1);     // out-CSR: key=src, skip self
    }
    __syncthreads();
    if (t < NBK) { hist1[b * NBK + t] = h1[t]; hist2[b * NBK + t] = h2[t]; }
}

// ---- sort phase 2: offsets per (bucket, block) + bucket starts ----
__global__ __launch_bounds__(256) void boffs_k(const int* __restrict__ hist,
        int* __restrict__ boffs, int* __restrict__ bstart) {
    int t = threadIdx.x;
    __shared__ int scn[256];
    int run = 0;
    if (t < NBK) {
        for (int b = 0; b < 256; ++b) {
            boffs[t * 256 + b] = run;
            run += hist[b * NBK + t];
        }
    }
    int v = (t < NBK) ? run : 0;
    scn[t] = v;
    __syncthreads();
    for (int off = 1; off < 256; off <<= 1) {
        int x = (t >= off) ? scn[t - off] : 0;
        __syncthreads();
        scn[t] += x;
        __syncthreads();
    }
    int excl = scn[t] - v;
    if (t < NBK) {
        bstart[t] = excl;
        if (t == NBK - 1) bstart[NBK] = excl + v;
        for (int b = 0; b < 256; ++b) boffs[t * 256 + b] += excl;
    }
}

// ---- sort phase 3: scatter both ebufs in one edge pass (LDS cursors) ----
__global__ __launch_bounds__(256) void scat_both_k(const int* __restrict__ ei,
        const int* __restrict__ boffs1, u32* __restrict__ ebuf1,
        const int* __restrict__ boffs2, u32* __restrict__ ebuf2) {
    __shared__ int c1[NBK], c2[NBK];
    int t = threadIdx.x, b = blockIdx.x;
    if (t < NBK) { c1[t] = boffs1[t * 256 + b]; c2[t] = boffs2[t * 256 + b]; }
    __syncthreads();
    int base = b * EPB;
    for (int i = t; i < EPB; i += 256) {
        int e = base + i;
        int s = ei[e], d = ei[EE + e];
        if ((u32)s >= NN || (u32)d >= NN) continue;
        int pos = atomicAdd(&c1[d >> 8], 1);
        ebuf1[pos] = (u32)s | ((u32)(d & 255) << 16);
        if (s != d) {
            int pos2 = atomicAdd(&c2[s >> 8], 1);
            ebuf2[pos2] = (u32)d | ((u32)(s & 255) << 16);
        }
    }
}

// ---- sort phase 4 body: per-bucket fine CSR fill (+ optional dinv) ----
__device__ __forceinline__ void fine_body(int bk, const u32* __restrict__ ebuf,
        const int* __restrict__ bstart, int* __restrict__ rowptr, u16* __restrict__ csrx,
        float* __restrict__ dinv, int addself) {
    __shared__ int cnt[256];
    __shared__ int scn[256];
    int t = threadIdx.x;
    int eb = bstart[bk], ee = bstart[bk + 1];
    cnt[t] = 0;
    __syncthreads();
    for (int i = eb + t; i < ee; i += 256)
        atomicAdd(&cnt[(ebuf[i] >> 16) & 255], 1);
    __syncthreads();
    int v = cnt[t];
    scn[t] = v;
    __syncthreads();
    for (int off = 1; off < 256; off <<= 1) {
        int x = (t >= off) ? scn[t - off] : 0;
        __syncthreads();
        scn[t] += x;
        __syncthreads();
    }
    int excl = scn[t] - v;
    int n = (bk << 8) + t;
    if (n < NN) {
        rowptr[n] = eb + excl;
        if (dinv) dinv[n] = 1.0f / sqrtf((float)(v + addself));
    }
    if (bk == NBK - 1 && t == 0) rowptr[NN] = ee;
    __syncthreads();
    cnt[t] = excl;   // reuse as cursor
    __syncthreads();
    for (int i = eb + t; i < ee; i += 256) {
        u32 w = ebuf[i];
        int lo = (w >> 16) & 255;
        int pos = atomicAdd(&cnt[lo], 1);
        csrx[eb + pos] = (u16)(w & 0xFFFF);
    }
}

__global__ __launch_bounds__(256) void fine2_k(const u32* __restrict__ ebuf1,
        const int* __restrict__ bstart1, int* __restrict__ irow, u16* __restrict__ csrc,
        float* __restrict__ dinv, const u32* __restrict__ ebuf2,
        const int* __restrict__ bstart2, int* __restrict__ orow, u16* __restrict__ ocol) {
    if (blockIdx.x < NBK) fine_body(blockIdx.x, ebuf1, bstart1, irow, csrc, dinv, 1);
    else                  fine_body(blockIdx.x - NBK, ebuf2, bstart2, orow, ocol, nullptr, 0);
}

// ---- pack weights: wt[mat][o][k] = bf16(W[k][o]); mats 0..2 conv, 3 = [sw1|hw1] ----
__global__ __launch_bounds__(256) void pack_w_k(const float* __restrict__ w0,
        const float* __restrict__ w1, const float* __restrict__ w2,
        const float* __restrict__ sw1, const float* __restrict__ hw1, u16* __restrict__ wt) {
    int i = blockIdx.x * 256 + threadIdx.x;
    if (i >= 4 * HH * HH) return;
    int mat = i >> 14, rr = i & 16383, o = rr >> 7, k = rr & 127;
    float v;
    if (mat == 0) v = w0[k * HH + o];
    else if (mat == 1) v = w1[k * HH + o];
    else if (mat == 2) v = w2[k * HH + o];
    else v = (o < CHH) ? sw1[k * CHH + o] : hw1[k * CHH + (o - CHH)];
    stbf(wt, (size_t)i, v);
}

// ---- MEGA: [hard_fin(li-1) pre-phase] + gather + conv GEMM + heads GEMM + soft ----
// block: 16 rows, 4 waves. sxPrev = cumulative softex through li-1 (read-only);
// sxOut = cumulative through li (own-node full overwrite). Races: none (see notes).
__global__ __launch_bounds__(256) void mega_k(int li, int geluf, int doHF,
        const int* __restrict__ irow, const u16* __restrict__ csrc, const float* __restrict__ dinv,
        const int* __restrict__ orow, const u16* __restrict__ ocol,
        const u16* __restrict__ hin_g, u16* __restrict__ hout_g,
        const u16* __restrict__ Wc, const u16* __restrict__ Wh, const float* __restrict__ bias,
        const float* __restrict__ sb1, const float* __restrict__ sw2, const float* __restrict__ sb2,
        const float* __restrict__ gs, const float* __restrict__ ghPrev,
        const int* __restrict__ sxPrev, int* __restrict__ sxOut,
        int* __restrict__ hardex, int* __restrict__ exitl,
        const float* __restrict__ hw1, const float* __restrict__ hb1,
        const float* __restrict__ hw2, const float* __restrict__ hb2,
        float* __restrict__ outP) {
    __shared__ u32 hin[16 * 64];                // swizzled gathered tile (u32 = 2 bf16)
    __shared__ u16 hl[16 * HH];                 // swizzled h tile for GEMM2
    __shared__ float l0s[2][16], l1s[2][16];
    __shared__ int hx[16];
    int tid = threadIdx.x;
    int wave = tid >> 6, lane = tid & 63;
    int row0 = blockIdx.x * 16;
    if (tid < 16) hx[tid] = hardex[row0 + tid];
    __syncthreads();
    // ---- phase 0: fused hard_fin for layer li-1 (own 16 nodes) ----
    if (doHF) {
        int lp = li - 1;
        for (int i = 0; i < 4; ++i) {
            int row = wave * 4 + i;
            int n = row0 + row;
            if (sxPrev[n] && !hx[row]) {       // wave-uniform
                int ob = orow[n], oe = orow[n + 1];
                int cnt = 0;
                for (int e = ob + lane; e < oe; e += 64) cnt += sxPrev[ocol[e]];
                #pragma unroll
                for (int off = 32; off > 0; off >>= 1) cnt += __shfl_xor(cnt, off);
                int dns = oe - ob; if (dns < 1) dns = 1;
                float r = (float)cnt / (float)dns;
                float pv = outP[(size_t)n * HH + CHH + lane];
                float hid = fmaxf(pv + r * hw1[HH * CHH + lane] + hb1[lane], 0.f);
                float l0 = hid * hw2[lane * 2], l1 = hid * hw2[lane * 2 + 1];
                #pragma unroll
                for (int off = 32; off > 0; off >>= 1) {
                    l0 += __shfl_xor(l0, off);   // butterfly: identical on all lanes
                    l1 += __shfl_xor(l1, off);
                }
                const float* g = ghPrev + (size_t)n * 2;
                if (l1 + hb2[1] + g[1] > l0 + hb2[0] + g[0]) {
                    if (lane == 0) { hardex[n] = 1; exitl[n] = lp; hx[row] = 1; }
                    u32 hw_ = *(const u32*)(hin_g + (size_t)n * HH + lane * 2);
                    outP[(size_t)n * HH + lane * 2]     = blo(hw_);   // z snapshot (h after lp)
                    outP[(size_t)n * HH + lane * 2 + 1] = bhi(hw_);
                }
            }
        }
        __syncthreads();
    }
    // ---- phase 1: gather 4 nodes per wave into swizzled LDS (unroll 8/2/1) ----
    #pragma unroll
    for (int i = 0; i < 4; ++i) {
        int row = wave * 4 + i;
        int node = row0 + row;
        int beg = irow[node], end = irow[node + 1];
        float dvd = dinv[node];
        float a0 = 0.f, a1 = 0.f;
        int e = beg;
        for (; e + 7 < end; e += 8) {
            int s0 = csrc[e], s1 = csrc[e+1], s2 = csrc[e+2], s3 = csrc[e+3];
            int s4 = csrc[e+4], s5 = csrc[e+5], s6 = csrc[e+6], s7 = csrc[e+7];
            float n0 = dinv[s0], n1 = dinv[s1], n2 = dinv[s2], n3 = dinv[s3];
            float n4 = dinv[s4], n5 = dinv[s5], n6 = dinv[s6], n7 = dinv[s7];
            u32 w0 = *(const u32*)(hin_g + (size_t)s0 * HH + lane * 2);
            u32 w1 = *(const u32*)(hin_g + (size_t)s1 * HH + lane * 2);
            u32 w2 = *(const u32*)(hin_g + (size_t)s2 * HH + lane * 2);
            u32 w3 = *(const u32*)(hin_g + (size_t)s3 * HH + lane * 2);
            u32 w4 = *(const u32*)(hin_g + (size_t)s4 * HH + lane * 2);
            u32 w5 = *(const u32*)(hin_g + (size_t)s5 * HH + lane * 2);
            u32 w6 = *(const u32*)(hin_g + (size_t)s6 * HH + lane * 2);
            u32 w7 = *(const u32*)(hin_g + (size_t)s7 * HH + lane * 2);
            a0 = fmaf(n0, blo(w0), a0); a1 = fmaf(n0, bhi(w0), a1);
            a0 = fmaf(n1, blo(w1), a0); a1 = fmaf(n1, bhi(w1), a1);
            a0 = fmaf(n2, blo(w2), a0); a1 = fmaf(n2, bhi(w2), a1);
            a0 = fmaf(n3, blo(w3), a0); a1 = fmaf(n3, bhi(w3), a1);
            a0 = fmaf(n4, blo(w4), a0); a1 = fmaf(n4, bhi(w4), a1);
            a0 = fmaf(n5, blo(w5), a0); a1 = fmaf(n5, bhi(w5), a1);
            a0 = fmaf(n6, blo(w6), a0); a1 = fmaf(n6, bhi(w6), a1);
            a0 = fmaf(n7, blo(w7), a0); a1 = fmaf(n7, bhi(w7), a1);
        }
        for (; e + 1 < end; e += 2) {
            int s0 = csrc[e], s1 = csrc[e + 1];
            float n0 = dinv[s0], n1 = dinv[s1];
            u32 w0 = *(const u32*)(hin_g + (size_t)s0 * HH + lane * 2);
            u32 w1 = *(const u32*)(hin_g + (size_t)s1 * HH + lane * 2);
            a0 = fmaf(n0, blo(w0), a0); a1 = fmaf(n0, bhi(w0), a1);
            a0 = fmaf(n1, blo(w1), a0); a1 = fmaf(n1, bhi(w1), a1);
        }
        if (e < end) {
            int s0 = csrc[e];
            float n0 = dinv[s0];
            u32 w0 = *(const u32*)(hin_g + (size_t)s0 * HH + lane * 2);
            a0 = fmaf(n0, blo(w0), a0); a1 = fmaf(n0, bhi(w0), a1);
        }
        a0 *= dvd; a1 *= dvd;
        u32 hw_ = *(const u32*)(hin_g + (size_t)node * HH + lane * 2);
        float self = dvd * dvd;                 // self-loop norm (ref gcn_norm)
        a0 = fmaf(blo(hw_), self, a0);
        a1 = fmaf(bhi(hw_), self, a1);
        hin[row * 64 + (((lane >> 2) ^ (row & 7)) << 2) + (lane & 3)] =
            (u32)f2b(a0) | ((u32)f2b(a1) << 16);
    }
    __syncthreads();
    // ---- phase 2: GEMM1 (conv) ----
    int r = lane & 15, g = lane >> 4;
    const u16* hinw = (const u16*)hin;
    s16x8 af[4];
    #pragma unroll
    for (int kk = 0; kk < 4; ++kk) {
        int chunk = (kk * 4 + g) ^ (r & 7);
        af[kk] = *(const s16x8*)(hinw + r * HH + chunk * 8);
    }
    f32x4 acc[2];
    #pragma unroll
    for (int cc = 0; cc < 2; ++cc) {
        int c0 = wave * 32 + cc * 16;
        const u16* brow = Wc + (size_t)(c0 + r) * HH;
        f32x4 a = {0.f, 0.f, 0.f, 0.f};
        #pragma unroll
        for (int kk = 0; kk < 4; ++kk) {
            s16x8 b = *(const s16x8*)(brow + kk * 32 + g * 8);
            a = __builtin_amdgcn_mfma_f32_16x16x32_bf16(af[kk], b, a, 0, 0, 0);
        }
        acc[cc] = a;
    }
    #pragma unroll
    for (int cc = 0; cc < 2; ++cc) {
        int col = wave * 32 + cc * 16 + r;
        float bv = bias[col];
        #pragma unroll
        for (int j = 0; j < 4; ++j) {
            int row = g * 4 + j;
            float v = acc[cc][j] + bv;
            if (geluf) v = 0.5f * v * (1.0f + erff(v * 0.70710678118654752f));
            stbf(hout_g, (size_t)(row0 + row) * HH + col, v);
            int chunk = (col >> 3) ^ (row & 7);            // XOR swizzle (G4)
            hl[row * HH + chunk * 8 + (col & 7)] = f2b(v);
        }
    }
    __syncthreads();
    // ---- phase 3: GEMM2 (heads) ----
    #pragma unroll
    for (int kk = 0; kk < 4; ++kk) {
        int k0 = kk * 32 + g * 8;
        int chunk = (k0 >> 3) ^ (r & 7);
        af[kk] = *(const s16x8*)(hl + r * HH + chunk * 8);
    }
    #pragma unroll
    for (int cc = 0; cc < 2; ++cc) {
        int c0 = wave * 32 + cc * 16;
        const u16* brow = Wh + (size_t)(c0 + r) * HH;
        f32x4 a = {0.f, 0.f, 0.f, 0.f};
        #pragma unroll
        for (int kk = 0; kk < 4; ++kk) {
            s16x8 b = *(const s16x8*)(brow + kk * 32 + g * 8);
            a = __builtin_amdgcn_mfma_f32_16x16x32_bf16(af[kk], b, a, 0, 0, 0);
        }
        acc[cc] = a;
    }
    if (wave < 2) {
        // soft half (cols 0..63): in-register hidden + logit partials
        float pl0[4] = {0.f, 0.f, 0.f, 0.f}, pl1[4] = {0.f, 0.f, 0.f, 0.f};
        #pragma unroll
        for (int cc = 0; cc < 2; ++cc) {
            int col = wave * 32 + cc * 16 + r;
            float b1 = sb1[col], w20 = sw2[col * 2], w21 = sw2[col * 2 + 1];
            #pragma unroll
            for (int j = 0; j < 4; ++j) {
                float hv = fmaxf(acc[cc][j] + b1, 0.f);
                pl0[j] = fmaf(hv, w20, pl0[j]);
                pl1[j] = fmaf(hv, w21, pl1[j]);
            }
        }
        #pragma unroll
        for (int off = 1; off < 16; off <<= 1) {
            #pragma unroll
            for (int j = 0; j < 4; ++j) {
                pl0[j] += __shfl_xor(pl0[j], off);
                pl1[j] += __shfl_xor(pl1[j], off);
            }
        }
        if (r == 0) {
            #pragma unroll
            for (int j = 0; j < 4; ++j) {
                l0s[wave][g * 4 + j] = pl0[j];
                l1s[wave][g * 4 + j] = pl1[j];
            }
        }
    } else {
        // hard half (cols 64..127): f32 P into out z-region, only not-yet-exited rows
        #pragma unroll
        for (int cc = 0; cc < 2; ++cc) {
            int col = wave * 32 + cc * 16 + r;
            #pragma unroll
            for (int j = 0; j < 4; ++j) {
                int row = g * 4 + j;
                if (!hx[row]) outP[(size_t)(row0 + row) * HH + col] = acc[cc][j];
            }
        }
    }
    __syncthreads();
    if (tid < 16) {
        int n = row0 + tid;
        float l0 = l0s[0][tid] + l0s[1][tid] + sb2[0];
        float l1 = l1s[0][tid] + l1s[1][tid] + sb2[1];
        const float* gg = gs + ((size_t)li * NN + n) * 2;
        int dec = (l1 + gg[1] > l0 + gg[0]) ? 1 : 0;
        sxOut[n] = sxPrev[n] | dec;            // cumulative through li
    }
}

// ---- standalone hard finish (last layer) ----
__global__ __launch_bounds__(256) void hard_fin_k(int li, const int* __restrict__ sx,
        const u16* __restrict__ h, const float* __restrict__ hw1, const float* __restrict__ hb1,
        const float* __restrict__ hw2, const float* __restrict__ hb2,
        const float* __restrict__ gh, int* __restrict__ hardex, int* __restrict__ exitl,
        const int* __restrict__ orow, const u16* __restrict__ ocol,
        float* __restrict__ out) {
    int t = threadIdx.x;
    int n = blockIdx.x * 4 + (t >> 6);
    int j = t & 63;
    if (!sx[n] || hardex[n]) return;   // wave-uniform
    int ob = orow[n], oe = orow[n + 1];
    int cnt = 0;
    for (int e = ob + j; e < oe; e += 64) cnt += sx[ocol[e]];
    #pragma unroll
    for (int off = 32; off > 0; off >>= 1) cnt += __shfl_xor(cnt, off);
    int dns = oe - ob; if (dns < 1) dns = 1;
    float r = (float)cnt / (float)dns;
    float pv = out[(size_t)n * HH + CHH + j];
    float hid = fmaxf(pv + r * hw1[HH * CHH + j] + hb1[j], 0.f);
    float l0 = hid * hw2[j * 2], l1 = hid * hw2[j * 2 + 1];
    #pragma unroll
    for (int off = 32; off > 0; off >>= 1) {
        l0 += __shfl_xor(l0, off);
        l1 += __shfl_xor(l1, off);
    }
    const float* g = gh + ((size_t)li * NN + n) * 2;
    if (l1 + hb2[1] + g[1] > l0 + hb2[0] + g[0]) {
        if (j == 0) { hardex[n] = 1; exitl[n] = li; }
        u32 hw_ = *(const u32*)(h + (size_t)n * HH + j * 2);
        out[(size_t)n * HH + j * 2]     = blo(hw_);
        out[(size_t)n * HH + j * 2 + 1] = bhi(hw_);
    }
}

// ---- tail: non-exited z rows + exit_layers; per-block exit histogram -> act ----
__global__ __launch_bounds__(256) void tail_k(const u16* __restrict__ h, const int* __restrict__ exitl,
        float* __restrict__ out, int* __restrict__ act) {
    __shared__ int c[LL];
    int t = threadIdx.x;
    int i = blockIdx.x * 256 + t;
    if (t < LL) c[t] = 0;
    __syncthreads();
    if (i < ZT) {
        int n = i >> 7;
        if (exitl[n] == LL) out[i] = ldbf(h, (size_t)i);
    } else if (i < ZT + NN) {
        int e = exitl[i - ZT];
        out[i] = (float)e;
        if (e < LL) atomicAdd(&c[e], 1);
    }
    __syncthreads();
    if (t < LL && c[t]) atomicAdd(&act[t], c[t]);
}

// ---- finalize active counts ----
__global__ __launch_bounds__(64) void finalize_k(const int* __restrict__ act, float* __restrict__ out) {
    if (threadIdx.x == 0) {
        out[ZT + NN]     = (float)NN;
        out[ZT + NN + 1] = (float)(NN - act[0]);
        out[ZT + NN + 2] = (float)(NN - act[0] - act[1]);
    }
}

extern "C" void kernel_launch(void* const* d_in, const int* in_sizes, int n_in,
                              void* d_out, int out_size, void* d_ws, size_t ws_size,
                              hipStream_t stream) {
    float* out = (float*)d_out;                 // output is FLOAT32
    const int OUT_N = ZT + NN + LL;

    static const int CANON[19] = {6400000,1600000,300000,300000,16384,128,16384,128,16384,128,
                                  8192,64,128,2,8256,64,128,2,128};
    static const int SORTED_ROLE[19] = {5,7,9,4,6,8,1,3,2,15,17,14,16,11,13,10,12,18,0};
    int perm[19];
    bool ok = (n_in == 19);
    if (ok) {
        bool mc = true, mr = true, ms = true;
        for (int i = 0; i < 19; ++i) {
            if (in_sizes[i] != CANON[i]) mc = false;
            if (in_sizes[i] != CANON[18 - i]) mr = false;
            if (in_sizes[i] != CANON[SORTED_ROLE[i]]) ms = false;
        }
        if (mc)      for (int c = 0; c < 19; ++c) perm[c] = c;
        else if (mr) for (int c = 0; c < 19; ++c) perm[c] = 18 - c;
        else if (ms) { for (int p = 0; p < 19; ++p) perm[SORTED_ROLE[p]] = p; }
        else         for (int c = 0; c < 19; ++c) perm[c] = c;
    }
    if (!ok) {
        zero_out_k<<<(OUT_N + 255) / 256, 256, 0, stream>>>(out, OUT_N);
        return;
    }

    const float* x  = (const float*)d_in[perm[0]];
    const int*   ei = (const int*)d_in[perm[1]];
    const float* gs = (const float*)d_in[perm[2]];
    const float* gh = (const float*)d_in[perm[3]];
    const float* cw[3] = { (const float*)d_in[perm[4]], (const float*)d_in[perm[6]], (const float*)d_in[perm[8]] };
    const float* cb[3] = { (const float*)d_in[perm[5]], (const float*)d_in[perm[7]], (const float*)d_in[perm[9]] };
    const float* sw1 = (const float*)d_in[perm[10]];
    const float* sb1 = (const float*)d_in[perm[11]];
    const float* sw2 = (const float*)d_in[perm[12]];
    const float* sb2 = (const float*)d_in[perm[13]];
    const float* hw1 = (const float*)d_in[perm[14]];
    const float* hb1 = (const float*)d_in[perm[15]];
    const float* hw2 = (const float*)d_in[perm[16]];
    const float* hb2 = (const float*)d_in[perm[17]];
    // temp_w unused: temp>0 always; softmax monotone -> decisions unaffected

    const size_t H_B    = (size_t)ZT * 2;      // 12.8 MB
    const size_t FLAG_B = 200192;
    const size_t ACT_B  = 256;
    const size_t RP_B   = 200704;              // 50001 ints padded
    const size_t CE_B   = (size_t)EE * 2;      // u16 CSR payloads
    const size_t WT_B   = 4 * HH * HH * 2;
    const size_t need = 2 * H_B + 5 * FLAG_B + ACT_B + 2 * RP_B + 2 * CE_B + WT_B;  // ~30.3 MB
    if (ws_size < need) {
        zero_out_k<<<(OUT_N + 255) / 256, 256, 0, stream>>>(out, OUT_N);
        return;
    }

    char* p = (char*)d_ws;
    u16* hA   = (u16*)p; p += H_B;
    u16* hB   = (u16*)p; p += H_B;             // sort scratch lives here pre-layers
    int* sx0    = (int*)p; p += FLAG_B;
    int* sx1    = (int*)p; p += FLAG_B;
    int* hardex = (int*)p; p += FLAG_B;
    int* exitl  = (int*)p; p += FLAG_B;
    float* dinv = (float*)p; p += FLAG_B;
    int* act    = (int*)p; p += ACT_B;
    int* irow   = (int*)p; p += RP_B;
    int* orow   = (int*)p; p += RP_B;
    u16* csrc   = (u16*)p; p += CE_B;
    u16* ocol   = (u16*)p; p += CE_B;
    u16* wt     = (u16*)p; p += WT_B;

    // sort scratch aliased into hB (dead until layer-0 GEMM writes hB)
    char* q = (char*)hB;
    u32* ebuf1  = (u32*)q;  q += (size_t)EE * 4;
    u32* ebuf2  = (u32*)q;  q += (size_t)EE * 4;
    int* hist1  = (int*)q;  q += 256 * NBK * 4;
    int* hist2  = (int*)q;  q += 256 * NBK * 4;
    int* boffs1 = (int*)q;  q += NBK * 256 * 4;
    int* boffs2 = (int*)q;  q += NBK * 256 * 4;
    int* bstart1 = (int*)q; q += 1024;
    int* bstart2 = (int*)q; q += 1024;

    init_k<<<(ZT + 255) / 256, 256, 0, stream>>>(x, hA, sx0, sx1, hardex, exitl, act);

    hist_both_k<<<256, 256, 0, stream>>>(ei, hist1, hist2);
    boffs_k<<<1, 256, 0, stream>>>(hist1, boffs1, bstart1);
    boffs_k<<<1, 256, 0, stream>>>(hist2, boffs2, bstart2);
    scat_both_k<<<256, 256, 0, stream>>>(ei, boffs1, ebuf1, boffs2, ebuf2);
    fine2_k<<<2 * NBK, 256, 0, stream>>>(ebuf1, bstart1, irow, csrc, dinv,
                                         ebuf2, bstart2, orow, ocol);
    pack_w_k<<<(4 * HH * HH + 255) / 256, 256, 0, stream>>>(cw[0], cw[1], cw[2], sw1, hw1, wt);

    u16* hbuf[2] = { hA, hB };
    int* sxb[2] = { sx0, sx1 };
    for (int li = 0; li < LL; ++li) {
        int geluf = (li < LL - 1) ? 1 : 0;
        u16* hin  = hbuf[li & 1];
        u16* hout = hbuf[(li & 1) ^ 1];
        const float* ghPrev = (li > 0) ? (gh + (size_t)(li - 1) * NN * 2) : gh;
        mega_k<<<NN / 16, 256, 0, stream>>>(li, geluf, li > 0 ? 1 : 0,
                                            irow, csrc, dinv, orow, ocol, hin, hout,
                                            wt + (size_t)li * HH * HH, wt + (size_t)3 * HH * HH,
                                            cb[li], sb1, sw2, sb2, gs, ghPrev,
                                            sxb[li & 1], sxb[(li + 1) & 1],
                                            hardex, exitl, hw1, hb1, hw2, hb2, out);
    }
    hard_fin_k<<<NN / 4, 256, 0, stream>>>(LL - 1, sxb[LL & 1], hbuf[LL & 1],
                                           hw1, hb1, hw2, hb2, gh,
                                           hardex, exitl, orow, ocol, out);
    tail_k<<<(OUT_N + 255) / 256, 256, 0, stream>>>(hbuf[LL & 1], exitl, out, act);
    finalize_k<<<1, 64, 0, stream>>>(act, out);
}

// Round 19
// 344.057 us; speedup vs baseline: 1.2693x; 1.0006x over previous
//
#include <hip/hip_runtime.h>
#include <hip/hip_bf16.h>
#include <math.h>

#define NN 50000
#define EE 800000
#define HH 128
#define CHH 64
#define LL 3
#define ZT (NN * HH)
#define NBK 196          // ceil(50000/256) node buckets
#define EPB 3125         // EE / 256 edges per sort block

using bf16 = __hip_bfloat16;
typedef unsigned short u16;
typedef unsigned int u32;
typedef __attribute__((ext_vector_type(8))) short s16x8;
typedef __attribute__((ext_vector_type(4))) float f32x4;

__device__ __forceinline__ float ldbf(const u16* p, size_t i) {
    return __uint_as_float(((u32)p[i]) << 16);
}
__device__ __forceinline__ u16 f2b(float v) {
    bf16 b = __float2bfloat16(v);
    return *reinterpret_cast<u16*>(&b);
}
__device__ __forceinline__ void stbf(u16* p, size_t i, float v) { p[i] = f2b(v); }
__device__ __forceinline__ float blo(u32 w) { return __uint_as_float(w << 16); }
__device__ __forceinline__ float bhi(u32 w) { return __uint_as_float(w & 0xFFFF0000u); }

// ---- zero-fill fallback (diagnostic signature) ----
__global__ __launch_bounds__(256) void zero_out_k(float* __restrict__ out, int n) {
    int i = blockIdx.x * 256 + threadIdx.x;
    if (i < n) out[i] = 0.f;
}

// ---- init: h=bf16(x), flags, both softex buffers ----
__global__ __launch_bounds__(256) void init_k(const float* __restrict__ x, u16* __restrict__ h,
        int* __restrict__ sx0, int* __restrict__ sx1, int* __restrict__ hardex,
        int* __restrict__ exitl, int* __restrict__ act) {
    int i = blockIdx.x * 256 + threadIdx.x;
    if (i < ZT) stbf(h, (size_t)i, x[i]);
    if (i < NN) { sx0[i] = 0; sx1[i] = 0; hardex[i] = 0; exitl[i] = LL; }
    if (i < LL) act[i] = 0;
}

// ---- sort phase 1: both bucket histograms in one edge pass ----
__global__ __launch_bounds__(256) void hist_both_k(const int* __restrict__ ei,
        int* __restrict__ hist1, int* __restrict__ hist2) {
    __shared__ int h1[NBK], h2[NBK];
    int t = threadIdx.x, b = blockIdx.x;
    if (t < NBK) { h1[t] = 0; h2[t] = 0; }
    __syncthreads();
    int base = b * EPB;
    for (int i = t; i < EPB; i += 256) {
        int e = base + i;
        int s = ei[e], d = ei[EE + e];
        if ((u32)s >= NN || (u32)d >= NN) continue;
        atomicAdd(&h1[d >> 8], 1);                 // in-CSR: key=dst, keep self
        if (s != d) atomicAdd(&h2[s >> 8], 1);     // out-CSR: key=src, skip self
    }
    __syncthreads();
    if (t < NBK) { hist1[b * NBK + t] = h1[t]; hist2[b * NBK + t] = h2[t]; }
}

// ---- sort phase 2 body + merged kernel (both CSRs in one launch) ----
__device__ __forceinline__ void boffs_body(const int* __restrict__ hist,
        int* __restrict__ boffs, int* __restrict__ bstart) {
    int t = threadIdx.x;
    __shared__ int scn[256];
    int run = 0;
    if (t < NBK) {
        for (int b = 0; b < 256; ++b) {
            boffs[t * 256 + b] = run;
            run += hist[b * NBK + t];
        }
    }
    int v = (t < NBK) ? run : 0;
    scn[t] = v;
    __syncthreads();
    for (int off = 1; off < 256; off <<= 1) {
        int x = (t >= off) ? scn[t - off] : 0;
        __syncthreads();
        scn[t] += x;
        __syncthreads();
    }
    int excl = scn[t] - v;
    if (t < NBK) {
        bstart[t] = excl;
        if (t == NBK - 1) bstart[NBK] = excl + v;
        for (int b = 0; b < 256; ++b) boffs[t * 256 + b] += excl;
    }
}

__global__ __launch_bounds__(256) void boffs2_k(const int* __restrict__ hist1,
        int* __restrict__ boffs1, int* __restrict__ bstart1, const int* __restrict__ hist2,
        int* __restrict__ boffs2, int* __restrict__ bstart2) {
    if (blockIdx.x == 0) boffs_body(hist1, boffs1, bstart1);
    else                 boffs_body(hist2, boffs2, bstart2);
}

// ---- sort phase 3: scatter both ebufs in one edge pass (LDS cursors) ----
__global__ __launch_bounds__(256) void scat_both_k(const int* __restrict__ ei,
        const int* __restrict__ boffs1, u32* __restrict__ ebuf1,
        const int* __restrict__ boffs2, u32* __restrict__ ebuf2) {
    __shared__ int c1[NBK], c2[NBK];
    int t = threadIdx.x, b = blockIdx.x;
    if (t < NBK) { c1[t] = boffs1[t * 256 + b]; c2[t] = boffs2[t * 256 + b]; }
    __syncthreads();
    int base = b * EPB;
    for (int i = t; i < EPB; i += 256) {
        int e = base + i;
        int s = ei[e], d = ei[EE + e];
        if ((u32)s >= NN || (u32)d >= NN) continue;
        int pos = atomicAdd(&c1[d >> 8], 1);
        ebuf1[pos] = (u32)s | ((u32)(d & 255) << 16);
        if (s != d) {
            int pos2 = atomicAdd(&c2[s >> 8], 1);
            ebuf2[pos2] = (u32)d | ((u32)(s & 255) << 16);
        }
    }
}

// ---- sort phase 4 body: per-bucket fine CSR fill (+ optional dinv) ----
__device__ __forceinline__ void fine_body(int bk, const u32* __restrict__ ebuf,
        const int* __restrict__ bstart, int* __restrict__ rowptr, u16* __restrict__ csrx,
        float* __restrict__ dinv, int addself) {
    __shared__ int cnt[256];
    __shared__ int scn[256];
    int t = threadIdx.x;
    int eb = bstart[bk], ee = bstart[bk + 1];
    cnt[t] = 0;
    __syncthreads();
    for (int i = eb + t; i < ee; i += 256)
        atomicAdd(&cnt[(ebuf[i] >> 16) & 255], 1);
    __syncthreads();
    int v = cnt[t];
    scn[t] = v;
    __syncthreads();
    for (int off = 1; off < 256; off <<= 1) {
        int x = (t >= off) ? scn[t - off] : 0;
        __syncthreads();
        scn[t] += x;
        __syncthreads();
    }
    int excl = scn[t] - v;
    int n = (bk << 8) + t;
    if (n < NN) {
        rowptr[n] = eb + excl;
        if (dinv) dinv[n] = 1.0f / sqrtf((float)(v + addself));
    }
    if (bk == NBK - 1 && t == 0) rowptr[NN] = ee;
    __syncthreads();
    cnt[t] = excl;   // reuse as cursor
    __syncthreads();
    for (int i = eb + t; i < ee; i += 256) {
        u32 w = ebuf[i];
        int lo = (w >> 16) & 255;
        int pos = atomicAdd(&cnt[lo], 1);
        csrx[eb + pos] = (u16)(w & 0xFFFF);
    }
}

__global__ __launch_bounds__(256) void fine2_k(const u32* __restrict__ ebuf1,
        const int* __restrict__ bstart1, int* __restrict__ irow, u16* __restrict__ csrc,
        float* __restrict__ dinv, const u32* __restrict__ ebuf2,
        const int* __restrict__ bstart2, int* __restrict__ orow, u16* __restrict__ ocol) {
    if (blockIdx.x < NBK) fine_body(blockIdx.x, ebuf1, bstart1, irow, csrc, dinv, 1);
    else                  fine_body(blockIdx.x - NBK, ebuf2, bstart2, orow, ocol, nullptr, 0);
}

// ---- pack weights: wt[mat][o][k] = bf16(W[k][o]); mats 0..2 conv, 3 = [sw1|hw1] ----
__global__ __launch_bounds__(256) void pack_w_k(const float* __restrict__ w0,
        const float* __restrict__ w1, const float* __restrict__ w2,
        const float* __restrict__ sw1, const float* __restrict__ hw1, u16* __restrict__ wt) {
    int i = blockIdx.x * 256 + threadIdx.x;
    if (i >= 4 * HH * HH) return;
    int mat = i >> 14, rr = i & 16383, o = rr >> 7, k = rr & 127;
    float v;
    if (mat == 0) v = w0[k * HH + o];
    else if (mat == 1) v = w1[k * HH + o];
    else if (mat == 2) v = w2[k * HH + o];
    else v = (o < CHH) ? sw1[k * CHH + o] : hw1[k * CHH + (o - CHH)];
    stbf(wt, (size_t)i, v);
}

// ---- MEGA: [hard_fin(li-1) pre-phase] + gather + conv GEMM + heads GEMM + soft ----
__global__ __launch_bounds__(256) void mega_k(int li, int geluf, int doHF,
        const int* __restrict__ irow, const u16* __restrict__ csrc, const float* __restrict__ dinv,
        const int* __restrict__ orow, const u16* __restrict__ ocol,
        const u16* __restrict__ hin_g, u16* __restrict__ hout_g,
        const u16* __restrict__ Wc, const u16* __restrict__ Wh, const float* __restrict__ bias,
        const float* __restrict__ sb1, const float* __restrict__ sw2, const float* __restrict__ sb2,
        const float* __restrict__ gs, const float* __restrict__ ghPrev,
        const int* __restrict__ sxPrev, int* __restrict__ sxOut,
        int* __restrict__ hardex, int* __restrict__ exitl,
        const float* __restrict__ hw1, const float* __restrict__ hb1,
        const float* __restrict__ hw2, const float* __restrict__ hb2,
        float* __restrict__ outP) {
    __shared__ u32 hin[16 * 64];                // swizzled gathered tile (u32 = 2 bf16)
    __shared__ u16 hl[16 * HH];                 // swizzled h tile for GEMM2
    __shared__ float l0s[2][16], l1s[2][16];
    __shared__ int hx[16];
    int tid = threadIdx.x;
    int wave = tid >> 6, lane = tid & 63;
    int row0 = blockIdx.x * 16;
    if (tid < 16) hx[tid] = hardex[row0 + tid];
    __syncthreads();
    // ---- phase 0: fused hard_fin for layer li-1 (own 16 nodes) ----
    if (doHF) {
        int lp = li - 1;
        for (int i = 0; i < 4; ++i) {
            int row = wave * 4 + i;
            int n = row0 + row;
            if (sxPrev[n] && !hx[row]) {       // wave-uniform
                int ob = orow[n], oe = orow[n + 1];
                int cnt = 0;
                for (int e = ob + lane; e < oe; e += 64) cnt += sxPrev[ocol[e]];
                #pragma unroll
                for (int off = 32; off > 0; off >>= 1) cnt += __shfl_xor(cnt, off);
                int dns = oe - ob; if (dns < 1) dns = 1;
                float r = (float)cnt / (float)dns;
                float pv = outP[(size_t)n * HH + CHH + lane];
                float hid = fmaxf(pv + r * hw1[HH * CHH + lane] + hb1[lane], 0.f);
                float l0 = hid * hw2[lane * 2], l1 = hid * hw2[lane * 2 + 1];
                #pragma unroll
                for (int off = 32; off > 0; off >>= 1) {
                    l0 += __shfl_xor(l0, off);   // butterfly: identical on all lanes
                    l1 += __shfl_xor(l1, off);
                }
                const float* g = ghPrev + (size_t)n * 2;
                if (l1 + hb2[1] + g[1] > l0 + hb2[0] + g[0]) {
                    if (lane == 0) { hardex[n] = 1; exitl[n] = lp; hx[row] = 1; }
                    u32 hw_ = *(const u32*)(hin_g + (size_t)n * HH + lane * 2);
                    outP[(size_t)n * HH + lane * 2]     = blo(hw_);   // z snapshot (h after lp)
                    outP[(size_t)n * HH + lane * 2 + 1] = bhi(hw_);
                }
            }
        }
        __syncthreads();
    }
    // ---- phase 1: gather 4 nodes per wave into swizzled LDS (unroll 8/2/1) ----
    #pragma unroll
    for (int i = 0; i < 4; ++i) {
        int row = wave * 4 + i;
        int node = row0 + row;
        int beg = irow[node], end = irow[node + 1];
        float dvd = dinv[node];
        float a0 = 0.f, a1 = 0.f;
        int e = beg;
        for (; e + 7 < end; e += 8) {
            int s0 = csrc[e], s1 = csrc[e+1], s2 = csrc[e+2], s3 = csrc[e+3];
            int s4 = csrc[e+4], s5 = csrc[e+5], s6 = csrc[e+6], s7 = csrc[e+7];
            float n0 = dinv[s0], n1 = dinv[s1], n2 = dinv[s2], n3 = dinv[s3];
            float n4 = dinv[s4], n5 = dinv[s5], n6 = dinv[s6], n7 = dinv[s7];
            u32 w0 = *(const u32*)(hin_g + (size_t)s0 * HH + lane * 2);
            u32 w1 = *(const u32*)(hin_g + (size_t)s1 * HH + lane * 2);
            u32 w2 = *(const u32*)(hin_g + (size_t)s2 * HH + lane * 2);
            u32 w3 = *(const u32*)(hin_g + (size_t)s3 * HH + lane * 2);
            u32 w4 = *(const u32*)(hin_g + (size_t)s4 * HH + lane * 2);
            u32 w5 = *(const u32*)(hin_g + (size_t)s5 * HH + lane * 2);
            u32 w6 = *(const u32*)(hin_g + (size_t)s6 * HH + lane * 2);
            u32 w7 = *(const u32*)(hin_g + (size_t)s7 * HH + lane * 2);
            a0 = fmaf(n0, blo(w0), a0); a1 = fmaf(n0, bhi(w0), a1);
            a0 = fmaf(n1, blo(w1), a0); a1 = fmaf(n1, bhi(w1), a1);
            a0 = fmaf(n2, blo(w2), a0); a1 = fmaf(n2, bhi(w2), a1);
            a0 = fmaf(n3, blo(w3), a0); a1 = fmaf(n3, bhi(w3), a1);
            a0 = fmaf(n4, blo(w4), a0); a1 = fmaf(n4, bhi(w4), a1);
            a0 = fmaf(n5, blo(w5), a0); a1 = fmaf(n5, bhi(w5), a1);
            a0 = fmaf(n6, blo(w6), a0); a1 = fmaf(n6, bhi(w6), a1);
            a0 = fmaf(n7, blo(w7), a0); a1 = fmaf(n7, bhi(w7), a1);
        }
        for (; e + 1 < end; e += 2) {
            int s0 = csrc[e], s1 = csrc[e + 1];
            float n0 = dinv[s0], n1 = dinv[s1];
            u32 w0 = *(const u32*)(hin_g + (size_t)s0 * HH + lane * 2);
            u32 w1 = *(const u32*)(hin_g + (size_t)s1 * HH + lane * 2);
            a0 = fmaf(n0, blo(w0), a0); a1 = fmaf(n0, bhi(w0), a1);
            a0 = fmaf(n1, blo(w1), a0); a1 = fmaf(n1, bhi(w1), a1);
        }
        if (e < end) {
            int s0 = csrc[e];
            float n0 = dinv[s0];
            u32 w0 = *(const u32*)(hin_g + (size_t)s0 * HH + lane * 2);
            a0 = fmaf(n0, blo(w0), a0); a1 = fmaf(n0, bhi(w0), a1);
        }
        a0 *= dvd; a1 *= dvd;
        u32 hw_ = *(const u32*)(hin_g + (size_t)node * HH + lane * 2);
        float self = dvd * dvd;                 // self-loop norm (ref gcn_norm)
        a0 = fmaf(blo(hw_), self, a0);
        a1 = fmaf(bhi(hw_), self, a1);
        hin[row * 64 + (((lane >> 2) ^ (row & 7)) << 2) + (lane & 3)] =
            (u32)f2b(a0) | ((u32)f2b(a1) << 16);
    }
    __syncthreads();
    // ---- phase 2: GEMM1 (conv) ----
    int r = lane & 15, g = lane >> 4;
    const u16* hinw = (const u16*)hin;
    s16x8 af[4];
    #pragma unroll
    for (int kk = 0; kk < 4; ++kk) {
        int chunk = (kk * 4 + g) ^ (r & 7);
        af[kk] = *(const s16x8*)(hinw + r * HH + chunk * 8);
    }
    f32x4 acc[2];
    #pragma unroll
    for (int cc = 0; cc < 2; ++cc) {
        int c0 = wave * 32 + cc * 16;
        const u16* brow = Wc + (size_t)(c0 + r) * HH;
        f32x4 a = {0.f, 0.f, 0.f, 0.f};
        #pragma unroll
        for (int kk = 0; kk < 4; ++kk) {
            s16x8 b = *(const s16x8*)(brow + kk * 32 + g * 8);
            a = __builtin_amdgcn_mfma_f32_16x16x32_bf16(af[kk], b, a, 0, 0, 0);
        }
        acc[cc] = a;
    }
    #pragma unroll
    for (int cc = 0; cc < 2; ++cc) {
        int col = wave * 32 + cc * 16 + r;
        float bv = bias[col];
        #pragma unroll
        for (int j = 0; j < 4; ++j) {
            int row = g * 4 + j;
            float v = acc[cc][j] + bv;
            if (geluf) v = 0.5f * v * (1.0f + erff(v * 0.70710678118654752f));
            stbf(hout_g, (size_t)(row0 + row) * HH + col, v);
            int chunk = (col >> 3) ^ (row & 7);            // XOR swizzle (G4)
            hl[row * HH + chunk * 8 + (col & 7)] = f2b(v);
        }
    }
    __syncthreads();
    // ---- phase 3: GEMM2 (heads) ----
    #pragma unroll
    for (int kk = 0; kk < 4; ++kk) {
        int k0 = kk * 32 + g * 8;
        int chunk = (k0 >> 3) ^ (r & 7);
        af[kk] = *(const s16x8*)(hl + r * HH + chunk * 8);
    }
    #pragma unroll
    for (int cc = 0; cc < 2; ++cc) {
        int c0 = wave * 32 + cc * 16;
        const u16* brow = Wh + (size_t)(c0 + r) * HH;
        f32x4 a = {0.f, 0.f, 0.f, 0.f};
        #pragma unroll
        for (int kk = 0; kk < 4; ++kk) {
            s16x8 b = *(const s16x8*)(brow + kk * 32 + g * 8);
            a = __builtin_amdgcn_mfma_f32_16x16x32_bf16(af[kk], b, a, 0, 0, 0);
        }
        acc[cc] = a;
    }
    if (wave < 2) {
        // soft half (cols 0..63): in-register hidden + logit partials
        float pl0[4] = {0.f, 0.f, 0.f, 0.f}, pl1[4] = {0.f, 0.f, 0.f, 0.f};
        #pragma unroll
        for (int cc = 0; cc < 2; ++cc) {
            int col = wave * 32 + cc * 16 + r;
            float b1 = sb1[col], w20 = sw2[col * 2], w21 = sw2[col * 2 + 1];
            #pragma unroll
            for (int j = 0; j < 4; ++j) {
                float hv = fmaxf(acc[cc][j] + b1, 0.f);
                pl0[j] = fmaf(hv, w20, pl0[j]);
                pl1[j] = fmaf(hv, w21, pl1[j]);
            }
        }
        #pragma unroll
        for (int off = 1; off < 16; off <<= 1) {
            #pragma unroll
            for (int j = 0; j < 4; ++j) {
                pl0[j] += __shfl_xor(pl0[j], off);
                pl1[j] += __shfl_xor(pl1[j], off);
            }
        }
        if (r == 0) {
            #pragma unroll
            for (int j = 0; j < 4; ++j) {
                l0s[wave][g * 4 + j] = pl0[j];
                l1s[wave][g * 4 + j] = pl1[j];
            }
        }
    } else {
        // hard half (cols 64..127): f32 P into out z-region, only not-yet-exited rows
        #pragma unroll
        for (int cc = 0; cc < 2; ++cc) {
            int col = wave * 32 + cc * 16 + r;
            #pragma unroll
            for (int j = 0; j < 4; ++j) {
                int row = g * 4 + j;
                if (!hx[row]) outP[(size_t)(row0 + row) * HH + col] = acc[cc][j];
            }
        }
    }
    __syncthreads();
    if (tid < 16) {
        int n = row0 + tid;
        float l0 = l0s[0][tid] + l0s[1][tid] + sb2[0];
        float l1 = l1s[0][tid] + l1s[1][tid] + sb2[1];
        const float* gg = gs + ((size_t)li * NN + n) * 2;
        int dec = (l1 + gg[1] > l0 + gg[0]) ? 1 : 0;
        sxOut[n] = sxPrev[n] | dec;            // cumulative through li
    }
}

// ---- FINISH: last-layer hard_fin + z fill + exit_layers + act histogram ----
// block = 128 nodes, 4 waves; wave handles 32 nodes serially in phase A
__global__ __launch_bounds__(256) void finish_k(const int* __restrict__ sx,
        const u16* __restrict__ h, const float* __restrict__ hw1, const float* __restrict__ hb1,
        const float* __restrict__ hw2, const float* __restrict__ hb2,
        const float* __restrict__ ghL, int* __restrict__ hardex, int* __restrict__ exitl,
        const int* __restrict__ orow, const u16* __restrict__ ocol,
        float* __restrict__ out, int* __restrict__ act) {
    __shared__ int c[LL];
    int t = threadIdx.x;
    int wave = t >> 6, lane = t & 63;
    int nbase = blockIdx.x * 128;
    if (t < LL) c[t] = 0;
    __syncthreads();
    // ---- phase A: hard finish for layer LL-1 ----
    for (int i = 0; i < 32; ++i) {
        int n = nbase + wave * 32 + i;
        if (n >= NN) break;
        if (!sx[n] || hardex[n]) continue;     // wave-uniform
        int ob = orow[n], oe = orow[n + 1];
        int cnt = 0;
        for (int e = ob + lane; e < oe; e += 64) cnt += sx[ocol[e]];
        #pragma unroll
        for (int off = 32; off > 0; off >>= 1) cnt += __shfl_xor(cnt, off);
        int dns = oe - ob; if (dns < 1) dns = 1;
        float r = (float)cnt / (float)dns;
        float pv = out[(size_t)n * HH + CHH + lane];
        float hid = fmaxf(pv + r * hw1[HH * CHH + lane] + hb1[lane], 0.f);
        float l0 = hid * hw2[lane * 2], l1 = hid * hw2[lane * 2 + 1];
        #pragma unroll
        for (int off = 32; off > 0; off >>= 1) {
            l0 += __shfl_xor(l0, off);         // butterfly: identical on all lanes
            l1 += __shfl_xor(l1, off);
        }
        const float* g = ghL + (size_t)n * 2;
        if (l1 + hb2[1] + g[1] > l0 + hb2[0] + g[0]) {
            if (lane == 0) { hardex[n] = 1; exitl[n] = LL - 1; }
            u32 hw_ = *(const u32*)(h + (size_t)n * HH + lane * 2);
            out[(size_t)n * HH + lane * 2]     = blo(hw_);
            out[(size_t)n * HH + lane * 2 + 1] = bhi(hw_);
        }
    }
    __syncthreads();
    // ---- phase B: z for never-exited + exit_layers + histogram ----
    for (int i = t; i < 128 * HH; i += 256) {
        int nn = nbase + (i >> 7);
        if (nn < NN && exitl[nn] == LL)
            out[(size_t)nn * HH + (i & 127)] = ldbf(h, (size_t)nn * HH + (i & 127));
    }
    if (t < 128) {
        int nn = nbase + t;
        if (nn < NN) {
            int e = exitl[nn];
            out[ZT + nn] = (float)e;
            if (e < LL) atomicAdd(&c[e], 1);   // LDS atomic
        }
    }
    __syncthreads();
    if (t < LL && c[t]) atomicAdd(&act[t], c[t]);  // 391 blocks x 3 atomics
}

// ---- finalize active counts ----
__global__ __launch_bounds__(64) void finalize_k(const int* __restrict__ act, float* __restrict__ out) {
    if (threadIdx.x == 0) {
        out[ZT + NN]     = (float)NN;
        out[ZT + NN + 1] = (float)(NN - act[0]);
        out[ZT + NN + 2] = (float)(NN - act[0] - act[1]);
    }
}

extern "C" void kernel_launch(void* const* d_in, const int* in_sizes, int n_in,
                              void* d_out, int out_size, void* d_ws, size_t ws_size,
                              hipStream_t stream) {
    float* out = (float*)d_out;                 // output is FLOAT32
    const int OUT_N = ZT + NN + LL;

    static const int CANON[19] = {6400000,1600000,300000,300000,16384,128,16384,128,16384,128,
                                  8192,64,128,2,8256,64,128,2,128};
    static const int SORTED_ROLE[19] = {5,7,9,4,6,8,1,3,2,15,17,14,16,11,13,10,12,18,0};
    int perm[19];
    bool ok = (n_in == 19);
    if (ok) {
        bool mc = true, mr = true, ms = true;
        for (int i = 0; i < 19; ++i) {
            if (in_sizes[i] != CANON[i]) mc = false;
            if (in_sizes[i] != CANON[18 - i]) mr = false;
            if (in_sizes[i] != CANON[SORTED_ROLE[i]]) ms = false;
        }
        if (mc)      for (int c = 0; c < 19; ++c) perm[c] = c;
        else if (mr) for (int c = 0; c < 19; ++c) perm[c] = 18 - c;
        else if (ms) { for (int p = 0; p < 19; ++p) perm[SORTED_ROLE[p]] = p; }
        else         for (int c = 0; c < 19; ++c) perm[c] = c;
    }
    if (!ok) {
        zero_out_k<<<(OUT_N + 255) / 256, 256, 0, stream>>>(out, OUT_N);
        return;
    }

    const float* x  = (const float*)d_in[perm[0]];
    const int*   ei = (const int*)d_in[perm[1]];
    const float* gs = (const float*)d_in[perm[2]];
    const float* gh = (const float*)d_in[perm[3]];
    const float* cw[3] = { (const float*)d_in[perm[4]], (const float*)d_in[perm[6]], (const float*)d_in[perm[8]] };
    const float* cb[3] = { (const float*)d_in[perm[5]], (const float*)d_in[perm[7]], (const float*)d_in[perm[9]] };
    const float* sw1 = (const float*)d_in[perm[10]];
    const float* sb1 = (const float*)d_in[perm[11]];
    const float* sw2 = (const float*)d_in[perm[12]];
    const float* sb2 = (const float*)d_in[perm[13]];
    const float* hw1 = (const float*)d_in[perm[14]];
    const float* hb1 = (const float*)d_in[perm[15]];
    const float* hw2 = (const float*)d_in[perm[16]];
    const float* hb2 = (const float*)d_in[perm[17]];
    // temp_w unused: temp>0 always; softmax monotone -> decisions unaffected

    const size_t H_B    = (size_t)ZT * 2;      // 12.8 MB
    const size_t FLAG_B = 200192;
    const size_t ACT_B  = 256;
    const size_t RP_B   = 200704;              // 50001 ints padded
    const size_t CE_B   = (size_t)EE * 2;      // u16 CSR payloads
    const size_t WT_B   = 4 * HH * HH * 2;
    const size_t need = 2 * H_B + 5 * FLAG_B + ACT_B + 2 * RP_B + 2 * CE_B + WT_B;  // ~30.3 MB
    if (ws_size < need) {
        zero_out_k<<<(OUT_N + 255) / 256, 256, 0, stream>>>(out, OUT_N);
        return;
    }

    char* p = (char*)d_ws;
    u16* hA   = (u16*)p; p += H_B;
    u16* hB   = (u16*)p; p += H_B;             // sort scratch lives here pre-layers
    int* sx0    = (int*)p; p += FLAG_B;
    int* sx1    = (int*)p; p += FLAG_B;
    int* hardex = (int*)p; p += FLAG_B;
    int* exitl  = (int*)p; p += FLAG_B;
    float* dinv = (float*)p; p += FLAG_B;
    int* act    = (int*)p; p += ACT_B;
    int* irow   = (int*)p; p += RP_B;
    int* orow   = (int*)p; p += RP_B;
    u16* csrc   = (u16*)p; p += CE_B;
    u16* ocol   = (u16*)p; p += CE_B;
    u16* wt     = (u16*)p; p += WT_B;

    // sort scratch aliased into hB (dead until layer-0 GEMM writes hB)
    char* q = (char*)hB;
    u32* ebuf1  = (u32*)q;  q += (size_t)EE * 4;
    u32* ebuf2  = (u32*)q;  q += (size_t)EE * 4;
    int* hist1  = (int*)q;  q += 256 * NBK * 4;
    int* hist2  = (int*)q;  q += 256 * NBK * 4;
    int* boffs1 = (int*)q;  q += NBK * 256 * 4;
    int* boffs2 = (int*)q;  q += NBK * 256 * 4;
    int* bstart1 = (int*)q; q += 1024;
    int* bstart2 = (int*)q; q += 1024;

    init_k<<<(ZT + 255) / 256, 256, 0, stream>>>(x, hA, sx0, sx1, hardex, exitl, act);

    hist_both_k<<<256, 256, 0, stream>>>(ei, hist1, hist2);
    boffs2_k<<<2, 256, 0, stream>>>(hist1, boffs1, bstart1, hist2, boffs2, bstart2);
    scat_both_k<<<256, 256, 0, stream>>>(ei, boffs1, ebuf1, boffs2, ebuf2);
    fine2_k<<<2 * NBK, 256, 0, stream>>>(ebuf1, bstart1, irow, csrc, dinv,
                                         ebuf2, bstart2, orow, ocol);
    pack_w_k<<<(4 * HH * HH + 255) / 256, 256, 0, stream>>>(cw[0], cw[1], cw[2], sw1, hw1, wt);

    u16* hbuf[2] = { hA, hB };
    int* sxb[2] = { sx0, sx1 };
    for (int li = 0; li < LL; ++li) {
        int geluf = (li < LL - 1) ? 1 : 0;
        u16* hin  = hbuf[li & 1];
        u16* hout = hbuf[(li & 1) ^ 1];
        const float* ghPrev = (li > 0) ? (gh + (size_t)(li - 1) * NN * 2) : gh;
        mega_k<<<NN / 16, 256, 0, stream>>>(li, geluf, li > 0 ? 1 : 0,
                                            irow, csrc, dinv, orow, ocol, hin, hout,
                                            wt + (size_t)li * HH * HH, wt + (size_t)3 * HH * HH,
                                            cb[li], sb1, sw2, sb2, gs, ghPrev,
                                            sxb[li & 1], sxb[(li + 1) & 1],
                                            hardex, exitl, hw1, hb1, hw2, hb2, out);
    }
    finish_k<<<(NN + 127) / 128, 256, 0, stream>>>(sxb[LL & 1], hbuf[LL & 1],
                                                   hw1, hb1, hw2, hb2,
                                                   gh + (size_t)(LL - 1) * NN * 2,
                                                   hardex, exitl, orow, ocol, out, act);
    finalize_k<<<1, 64, 0, stream>>>(act, out);
}